// Round 1
// baseline (509.495 us; speedup 1.0000x reference)
//
#include <hip/hip_runtime.h>
#include <hip/hip_bf16.h>
#include <cstdint>

// Problem constants
#define BATCH   4
#define SEQ     1024
#define DM      512
#define NH      8
#define DH      64
#define RH      64
#define ROWS    (BATCH*SEQ)          // 4096

// workspace float offsets
#define QOFF    0
#define KTOFF   (2*1024*1024)
#define VOFF    (4*1024*1024)
#define CTXOFF  (6*1024*1024)
#define AOFF    (8*1024*1024)
#define CTOFF   (8*1024*1024 + 256*1024)

// ---------------------------------------------------------------------------
// QKV projection: x(4096x512) @ {Wq,Wk,Wv}(512x512) + bias
// Writes Q,V as (b,h,s,dh); K transposed as (b,h,dh,s)
// 64x64 tile, 256 threads, 4x4 micro-tile, BK=16
// ---------------------------------------------------------------------------
__global__ __launch_bounds__(256) void gemm_qkv(
    const float* __restrict__ x,
    const float* __restrict__ Wq, const float* __restrict__ Wk, const float* __restrict__ Wv,
    const float* __restrict__ bq, const float* __restrict__ bk, const float* __restrict__ bv,
    float* __restrict__ Qw, float* __restrict__ Ktw, float* __restrict__ Vw)
{
    const int tx = threadIdx.x & 15, ty = threadIdx.x >> 4;
    const int m0 = blockIdx.y * 64;
    const int n0 = blockIdx.x * 64;          // 0..1535
    const int sec = n0 >> 9;                 // 0=Q 1=K 2=V
    const int nn0 = n0 & 511;

    const float* __restrict__ W    = (sec == 0) ? Wq : (sec == 1) ? Wk : Wv;
    const float* __restrict__ bias = (sec == 0) ? bq : (sec == 1) ? bk : bv;

    __shared__ __align__(16) float As[16][68];
    __shared__ __align__(16) float Ws[16][68];

    float acc[4][4];
    #pragma unroll
    for (int i = 0; i < 4; ++i)
        #pragma unroll
        for (int j = 0; j < 4; ++j) acc[i][j] = 0.f;

    const int lm = threadIdx.x >> 2;          // 0..63  A row
    const int lk = (threadIdx.x & 3) * 4;     // 0,4,8,12
    const int wk = ty;                        // 0..15  W row
    const int wn = tx * 4;                    // 0..60

    for (int k0 = 0; k0 < DM; k0 += 16) {
        float4 av = *(const float4*)&x[(size_t)(m0 + lm) * DM + k0 + lk];
        float4 wv4 = *(const float4*)&W[(size_t)(k0 + wk) * DM + nn0 + wn];
        __syncthreads();
        As[lk + 0][lm] = av.x;
        As[lk + 1][lm] = av.y;
        As[lk + 2][lm] = av.z;
        As[lk + 3][lm] = av.w;
        *(float4*)&Ws[wk][wn] = wv4;
        __syncthreads();
        #pragma unroll
        for (int k = 0; k < 16; ++k) {
            float4 a4 = *(const float4*)&As[k][ty * 4];
            float4 w4 = *(const float4*)&Ws[k][tx * 4];
            const float ar[4] = {a4.x, a4.y, a4.z, a4.w};
            const float wr[4] = {w4.x, w4.y, w4.z, w4.w};
            #pragma unroll
            for (int i = 0; i < 4; ++i)
                #pragma unroll
                for (int j = 0; j < 4; ++j)
                    acc[i][j] = fmaf(ar[i], wr[j], acc[i][j]);
        }
    }

    #pragma unroll
    for (int i = 0; i < 4; ++i) {
        const int m = m0 + ty * 4 + i;
        const int b = m >> 10, s = m & 1023;
        #pragma unroll
        for (int j = 0; j < 4; ++j) {
            const int n = nn0 + tx * 4 + j;
            const float v = acc[i][j] + bias[n];
            const int h = n >> 6, c = n & 63;
            if (sec == 0)      Qw [((size_t)(b * NH + h) * SEQ + s) * DH + c] = v;
            else if (sec == 1) Ktw[((size_t)(b * NH + h) * DH + c) * SEQ + s] = v;
            else               Vw [((size_t)(b * NH + h) * SEQ + s) * DH + c] = v;
        }
    }
}

// ---------------------------------------------------------------------------
// Output projection: ctx(4096x512) @ Wo + bo -> out
// ---------------------------------------------------------------------------
__global__ __launch_bounds__(256) void gemm_out(
    const float* __restrict__ A,
    const float* __restrict__ W,
    const float* __restrict__ bias,
    float* __restrict__ out)
{
    const int tx = threadIdx.x & 15, ty = threadIdx.x >> 4;
    const int m0 = blockIdx.y * 64;
    const int n0 = blockIdx.x * 64;

    __shared__ __align__(16) float As[16][68];
    __shared__ __align__(16) float Ws[16][68];

    float acc[4][4];
    #pragma unroll
    for (int i = 0; i < 4; ++i)
        #pragma unroll
        for (int j = 0; j < 4; ++j) acc[i][j] = 0.f;

    const int lm = threadIdx.x >> 2;
    const int lk = (threadIdx.x & 3) * 4;
    const int wk = ty;
    const int wn = tx * 4;

    for (int k0 = 0; k0 < DM; k0 += 16) {
        float4 av = *(const float4*)&A[(size_t)(m0 + lm) * DM + k0 + lk];
        float4 wv4 = *(const float4*)&W[(size_t)(k0 + wk) * DM + n0 + wn];
        __syncthreads();
        As[lk + 0][lm] = av.x;
        As[lk + 1][lm] = av.y;
        As[lk + 2][lm] = av.z;
        As[lk + 3][lm] = av.w;
        *(float4*)&Ws[wk][wn] = wv4;
        __syncthreads();
        #pragma unroll
        for (int k = 0; k < 16; ++k) {
            float4 a4 = *(const float4*)&As[k][ty * 4];
            float4 w4 = *(const float4*)&Ws[k][tx * 4];
            const float ar[4] = {a4.x, a4.y, a4.z, a4.w};
            const float wr[4] = {w4.x, w4.y, w4.z, w4.w};
            #pragma unroll
            for (int i = 0; i < 4; ++i)
                #pragma unroll
                for (int j = 0; j < 4; ++j)
                    acc[i][j] = fmaf(ar[i], wr[j], acc[i][j]);
        }
    }

    #pragma unroll
    for (int i = 0; i < 4; ++i) {
        const int m = m0 + ty * 4 + i;
        float4 o;
        o.x = acc[i][0] + bias[n0 + tx * 4 + 0];
        o.y = acc[i][1] + bias[n0 + tx * 4 + 1];
        o.z = acc[i][2] + bias[n0 + tx * 4 + 2];
        o.w = acc[i][3] + bias[n0 + tx * 4 + 3];
        *(float4*)&out[(size_t)m * DM + n0 + tx * 4] = o;
    }
}

// ---------------------------------------------------------------------------
// Relative-feature precompute:
//   A[row][k]  =  f*W1[0][k] + log(f+eps)*W1[1][k] + b1[k]      (query side)
//   Ct[b][k][j] = -(f*W1[0][k] + log(f+eps)*W1[1][k])           (key side, transposed)
// ---------------------------------------------------------------------------
__global__ __launch_bounds__(64) void rel_kernel(
    const float* __restrict__ freqs,
    const float* __restrict__ W1,
    const float* __restrict__ b1,
    float* __restrict__ Aw,
    float* __restrict__ Ctw)
{
    const int row = blockIdx.x;            // 0..4095
    const int b = row >> 10, s = row & 1023;
    const int k = threadIdx.x;             // 0..63
    const float f = freqs[row];
    const float L = logf(f + 1e-6f);
    const float w0 = W1[k], w1 = W1[RH + k];
    const float base = f * w0 + L * w1;
    Aw[(size_t)row * RH + k] = base + b1[k];
    Ctw[((size_t)b * RH + k) * SEQ + s] = -base;
}

// ---------------------------------------------------------------------------
// Attention: one block = (b, h, 8-query tile). 256 threads.
// Phase 1: scores S = Q·K^T/8 + bias  into LDS (8 x 1024)
// Phase 2: softmax (un-normalized p, 1/l saved)
// Phase 3: P @ V with j-sliced partials, combine, write ctx (b,s,h*64+c)
// ---------------------------------------------------------------------------
#define SSTR 1028   // LDS row stride for scores (pad 4)

__global__ __launch_bounds__(256) void attn_kernel(
    const float* __restrict__ Qw,
    const float* __restrict__ Ktw,
    const float* __restrict__ Vw,
    const float* __restrict__ Aw,
    const float* __restrict__ Ctw,
    const float* __restrict__ W2,
    float* __restrict__ ctx)
{
    const int t = threadIdx.x;
    const int blk = blockIdx.x;
    const int it = blk & 127;
    const int h  = (blk >> 7) & 7;
    const int b  = blk >> 10;
    const int s0 = it * 8;
    const int bh = b * NH + h;

    __shared__ __align__(16) float Ss[8 * SSTR];        // 32896 B
    __shared__ __align__(16) float Qst[64 * 12];        // [k][q], stride 12
    __shared__ __align__(16) float Ast[64 * 12];
    __shared__ __align__(16) float w2s[64];
    __shared__ float invl[8];

    // ---- load Q tile and A tile (transposed into [k][q]) + W2 column
    #pragma unroll
    for (int i = 0; i < 2; ++i) {
        const int idx = t + i * 256;             // 0..511
        const int q = idx >> 6, c = idx & 63;
        Qst[c * 12 + q] = Qw[((size_t)bh * SEQ + s0 + q) * DH + c];
        Ast[c * 12 + q] = Aw[((size_t)b * SEQ + s0 + q) * RH + c];
    }
    if (t < 64) w2s[t] = W2[t * NH + h];
    __syncthreads();

    // ---- phase 1: scores
    {
        const int qg = t >> 7;          // 0..1 -> queries qg*4 .. qg*4+3
        const int tj = t & 127;
        const float* __restrict__ KtBase = Ktw + (size_t)bh * DH * SEQ;
        const float* __restrict__ CtBase = Ctw + (size_t)b * RH * SEQ;

        for (int step = 0; step < 2; ++step) {
            const int j0 = step * 512 + tj * 4;
            float sc[4][4], sb[4][4];
            #pragma unroll
            for (int qi = 0; qi < 4; ++qi)
                #pragma unroll
                for (int jj = 0; jj < 4; ++jj) { sc[qi][jj] = 0.f; sb[qi][jj] = 0.f; }

            #pragma unroll 4
            for (int k = 0; k < 64; ++k) {
                const float4 kt4 = *(const float4*)&KtBase[k * SEQ + j0];
                const float4 ct4 = *(const float4*)&CtBase[k * SEQ + j0];
                const float4 q4  = *(const float4*)&Qst[k * 12 + qg * 4];
                const float4 a4  = *(const float4*)&Ast[k * 12 + qg * 4];
                const float w = w2s[k];
                const float kk[4] = {kt4.x, kt4.y, kt4.z, kt4.w};
                const float cc[4] = {ct4.x, ct4.y, ct4.z, ct4.w};
                const float qa[4] = {q4.x, q4.y, q4.z, q4.w};
                const float aa[4] = {a4.x, a4.y, a4.z, a4.w};
                #pragma unroll
                for (int qi = 0; qi < 4; ++qi) {
                    #pragma unroll
                    for (int jj = 0; jj < 4; ++jj) {
                        sc[qi][jj] = fmaf(qa[qi], kk[jj], sc[qi][jj]);
                        const float hh = fmaxf(aa[qi] + cc[jj], 0.f);
                        sb[qi][jj] = fmaf(hh, w, sb[qi][jj]);
                    }
                }
            }
            #pragma unroll
            for (int qi = 0; qi < 4; ++qi) {
                const int q = qg * 4 + qi;
                float4 o;
                o.x = sc[qi][0] * 0.125f + sb[qi][0];
                o.y = sc[qi][1] * 0.125f + sb[qi][1];
                o.z = sc[qi][2] * 0.125f + sb[qi][2];
                o.w = sc[qi][3] * 0.125f + sb[qi][3];
                *(float4*)&Ss[q * SSTR + j0] = o;
            }
        }
    }
    __syncthreads();

    // ---- phase 2: softmax over each row of 1024
    {
        const int qi = t >> 5;          // 0..7
        const int ln = t & 31;
        const int base = qi * SSTR;
        float m = -1e30f;
        #pragma unroll 8
        for (int jj = 0; jj < 32; ++jj)
            m = fmaxf(m, Ss[base + ln + jj * 32]);
        #pragma unroll
        for (int mask = 16; mask >= 1; mask >>= 1)
            m = fmaxf(m, __shfl_xor(m, mask));
        float l = 0.f;
        #pragma unroll 8
        for (int jj = 0; jj < 32; ++jj) {
            const int id = base + ln + jj * 32;
            const float p = __expf(Ss[id] - m);
            Ss[id] = p;
            l += p;
        }
        #pragma unroll
        for (int mask = 16; mask >= 1; mask >>= 1)
            l += __shfl_xor(l, mask);
        if (ln == 0) invl[qi] = 1.0f / l;
    }
    __syncthreads();

    // ---- phase 3: P @ V (j-sliced partials)
    {
        const int tc  = t & 15;
        const int qg2 = (t >> 4) & 1;
        const int jg  = t >> 5;          // 0..7
        const int c0  = tc * 4;
        const int q0  = qg2 * 4;
        const float* __restrict__ Vbase = Vw + (size_t)bh * SEQ * DH;

        float ac[4][4];
        #pragma unroll
        for (int qi = 0; qi < 4; ++qi)
            #pragma unroll
            for (int cc2 = 0; cc2 < 4; ++cc2) ac[qi][cc2] = 0.f;

        #pragma unroll 4
        for (int jj = 0; jj < 128; ++jj) {
            const int j = jg * 128 + jj;
            const float4 v4 = *(const float4*)&Vbase[j * DH + c0];
            const float vv[4] = {v4.x, v4.y, v4.z, v4.w};
            #pragma unroll
            for (int qi = 0; qi < 4; ++qi) {
                const float p = Ss[(q0 + qi) * SSTR + j];
                #pragma unroll
                for (int cc2 = 0; cc2 < 4; ++cc2)
                    ac[qi][cc2] = fmaf(p, vv[cc2], ac[qi][cc2]);
            }
        }
        __syncthreads();   // all Ss reads done; safe to reuse as partial buffer

        float* __restrict__ Op = Ss;     // [jg][q][c] : 8*8*64
        #pragma unroll
        for (int qi = 0; qi < 4; ++qi) {
            float4 o;
            o.x = ac[qi][0]; o.y = ac[qi][1]; o.z = ac[qi][2]; o.w = ac[qi][3];
            *(float4*)&Op[jg * 512 + (q0 + qi) * 64 + c0] = o;
        }
        __syncthreads();

        #pragma unroll
        for (int i = 0; i < 2; ++i) {
            const int idx = t + i * 256;          // 0..511
            const int q = idx >> 6, c = idx & 63;
            float sum = 0.f;
            #pragma unroll
            for (int jg2 = 0; jg2 < 8; ++jg2)
                sum += Op[jg2 * 512 + idx];
            ctx[((size_t)(b * SEQ) + s0 + q) * DM + h * DH + c] = sum * invl[q];
        }
    }
}

// ---------------------------------------------------------------------------
extern "C" void kernel_launch(void* const* d_in, const int* in_sizes, int n_in,
                              void* d_out, int out_size, void* d_ws, size_t ws_size,
                              hipStream_t stream)
{
    const float* x     = (const float*)d_in[0];
    const float* freqs = (const float*)d_in[1];
    const float* Wq    = (const float*)d_in[2];
    const float* bq    = (const float*)d_in[3];
    const float* Wk    = (const float*)d_in[4];
    const float* bk    = (const float*)d_in[5];
    const float* Wv    = (const float*)d_in[6];
    const float* bv    = (const float*)d_in[7];
    const float* Wo    = (const float*)d_in[8];
    const float* bo    = (const float*)d_in[9];
    const float* W1    = (const float*)d_in[10];
    const float* b1    = (const float*)d_in[11];
    const float* W2    = (const float*)d_in[12];
    // b2 (d_in[13]) is softmax-invariant: dropped.

    float* ws  = (float*)d_ws;
    float* Qw  = ws + QOFF;
    float* Ktw = ws + KTOFF;
    float* Vw  = ws + VOFF;
    float* ctx = ws + CTXOFF;
    float* Aw  = ws + AOFF;
    float* Ctw = ws + CTOFF;
    float* out = (float*)d_out;

    gemm_qkv<<<dim3(24, 64), 256, 0, stream>>>(x, Wq, Wk, Wv, bq, bk, bv, Qw, Ktw, Vw);
    rel_kernel<<<dim3(4096), 64, 0, stream>>>(freqs, W1, b1, Aw, Ctw);
    attn_kernel<<<dim3(4096), 256, 0, stream>>>(Qw, Ktw, Vw, Aw, Ctw, W2, ctx);
    gemm_out<<<dim3(8, 64), 256, 0, stream>>>(ctx, Wo, bo, out);
}